// Round 1
// baseline (505.483 us; speedup 1.0000x reference)
//
#include <hip/hip_runtime.h>
#include <hip/hip_bf16.h>

#define BB 4
#define SS 2048
#define DD 1024
#define HH 16
#define DHH 64

typedef __attribute__((ext_vector_type(8))) short short8;
typedef __attribute__((ext_vector_type(4))) float floatx4;

__device__ inline short f2bf(float x) {
  union { float f; unsigned u; } v; v.f = x;
  unsigned r = v.u + 0x7FFFu + ((v.u >> 16) & 1u);
  return (short)(r >> 16);
}
__device__ inline float bf2f(short x) {
  union { unsigned u; float f; } v;
  v.u = ((unsigned)(unsigned short)x) << 16;
  return v.f;
}

// ---------------- f32 -> bf16 conversion (vectorized) ----------------
__global__ __launch_bounds__(256) void cvt_kernel(const float* __restrict__ in,
                                                  short* __restrict__ out, int n4) {
  int i = blockIdx.x * 256 + threadIdx.x;
  if (i >= n4) return;
  float4 v = ((const float4*)in)[i];
  short4 o;
  o.x = f2bf(v.x); o.y = f2bf(v.y); o.z = f2bf(v.z); o.w = f2bf(v.w);
  ((short4*)out)[i] = o;
}

// ---------------- weight transpose + convert (+scale) ----------------
// in: [1024,1024] f32 row-major (K,N). out: [1024,1024] bf16 (N,K).
__global__ __launch_bounds__(256) void wtrans_kernel(const float* __restrict__ in,
                                                     short* __restrict__ out, float scale) {
  __shared__ float tile[16][17];
  int tx = threadIdx.x & 15, ty = threadIdx.x >> 4;
  int k = blockIdx.y * 16 + ty;
  int n = blockIdx.x * 16 + tx;
  tile[ty][tx] = in[(size_t)k * 1024 + n];
  __syncthreads();
  int n2 = blockIdx.x * 16 + ty;
  int k2 = blockIdx.y * 16 + tx;
  out[(size_t)n2 * 1024 + k2] = f2bf(tile[tx][ty] * scale);
}

// ---------------- bf16 MFMA GEMM: C[M,N] = A[M,K] @ Bt[N,K]^T ----------------
// 128x128 tile, BK=32, 256 threads = 4 waves, each wave 64x64 (4x4 frags of 16x16).
template<int OUT_F32>
__global__ __launch_bounds__(256) void gemm_kernel(const short* __restrict__ A,
                                                   const short* __restrict__ Bt,
                                                   void* __restrict__ Cout,
                                                   int M, int N, int K) {
  __shared__ short As[128][48];
  __shared__ short Bs[128][48];
  const int t = threadIdx.x;
  const int lane = t & 63, wave = t >> 6;
  const int wr = wave >> 1, wc = wave & 1;
  const int l15 = lane & 15, l4 = lane >> 4;

  floatx4 acc[4][4];
#pragma unroll
  for (int i = 0; i < 4; ++i)
#pragma unroll
    for (int j = 0; j < 4; ++j) acc[i][j] = (floatx4){0.f, 0.f, 0.f, 0.f};

  const short* Ag = A + (size_t)blockIdx.x * 128 * K;
  const short* Bg = Bt + (size_t)blockIdx.y * 128 * K;
  const int stRow = t >> 2;          // 0..63
  const int stG = (t & 3) * 8;       // 0,8,16,24
  const int rbase = wr * 64 + l15;
  const int cbase = wc * 64 + l15;
  const int koff = l4 * 8;

  for (int k0 = 0; k0 < K; k0 += 32) {
    __syncthreads();
#pragma unroll
    for (int i = 0; i < 2; ++i) {
      int row = stRow + i * 64;
      *(short8*)&As[row][stG] = *(const short8*)&Ag[(size_t)row * K + k0 + stG];
      *(short8*)&Bs[row][stG] = *(const short8*)&Bg[(size_t)row * K + k0 + stG];
    }
    __syncthreads();
    short8 af[4], bfr[4];
#pragma unroll
    for (int mi = 0; mi < 4; ++mi) af[mi] = *(const short8*)&As[rbase + mi * 16][koff];
#pragma unroll
    for (int ni = 0; ni < 4; ++ni) bfr[ni] = *(const short8*)&Bs[cbase + ni * 16][koff];
#pragma unroll
    for (int mi = 0; mi < 4; ++mi)
#pragma unroll
      for (int ni = 0; ni < 4; ++ni)
        acc[mi][ni] = __builtin_amdgcn_mfma_f32_16x16x32_bf16(af[mi], bfr[ni], acc[mi][ni], 0, 0, 0);
  }

  const int row0 = blockIdx.x * 128 + wr * 64 + l4 * 4;
  const int col0 = blockIdx.y * 128 + wc * 64 + l15;
  if (OUT_F32) {
    float* Cf = (float*)Cout;
#pragma unroll
    for (int mi = 0; mi < 4; ++mi)
#pragma unroll
      for (int ni = 0; ni < 4; ++ni)
#pragma unroll
        for (int r = 0; r < 4; ++r)
          Cf[(size_t)(row0 + mi * 16 + r) * N + col0 + ni * 16] = acc[mi][ni][r];
  } else {
    short* Cs = (short*)Cout;
#pragma unroll
    for (int mi = 0; mi < 4; ++mi)
#pragma unroll
      for (int ni = 0; ni < 4; ++ni)
#pragma unroll
        for (int r = 0; r < 4; ++r)
          Cs[(size_t)(row0 + mi * 16 + r) * N + col0 + ni * 16] = f2bf(acc[mi][ni][r]);
  }
}

// ---------------- flash attention ----------------
// grid: (B*H, S/64). 256 threads = 4 waves; wave w owns q rows [q0+16w, q0+16w+16).
// K tile [64][64] row-major LDS; V tile transposed [d][kv]; P via per-wave LDS.
__global__ __launch_bounds__(256) void attn_kernel(const short* __restrict__ Q,
                                                   const short* __restrict__ K,
                                                   const short* __restrict__ V,
                                                   const short* __restrict__ biasb,
                                                   short* __restrict__ O) {
  __shared__ short Klds[64][72];
  __shared__ short Vt[64][72];
  __shared__ short Plds[4][16][72];

  const int t = threadIdx.x;
  const int lane = t & 63, wave = t >> 6;
  const int b = blockIdx.x >> 4, h = blockIdx.x & 15;
  const int q0 = blockIdx.y * 64;
  const int l15 = lane & 15, l4 = lane >> 4;

  const size_t headoff = (size_t)h * DHH;
  const short* Qb = Q + (size_t)b * SS * DD + headoff;
  const short* Kb = K + (size_t)b * SS * DD + headoff;
  const short* Vb = V + (size_t)b * SS * DD + headoff;

  short8 aq[2];
  {
    int qrow = q0 + wave * 16 + l15;
    aq[0] = *(const short8*)&Qb[(size_t)qrow * DD + l4 * 8];
    aq[1] = *(const short8*)&Qb[(size_t)qrow * DD + 32 + l4 * 8];
  }

  floatx4 acc_o[4];
#pragma unroll
  for (int dg = 0; dg < 4; ++dg) acc_o[dg] = (floatx4){0.f, 0.f, 0.f, 0.f};
  float mrun[4], ssum[4];
#pragma unroll
  for (int r = 0; r < 4; ++r) { mrun[r] = -1e30f; ssum[r] = 0.f; }

  for (int kv0 = 0; kv0 < SS; kv0 += 64) {
    __syncthreads();  // previous iter's LDS reads done before restaging
#pragma unroll
    for (int i = 0; i < 2; ++i) {
      int idx = t + i * 256;
      int kv = idx >> 3, g = (idx & 7) * 8;
      *(short8*)&Klds[kv][g] = *(const short8*)&Kb[(size_t)(kv0 + kv) * DD + g];
      short8 vv = *(const short8*)&Vb[(size_t)(kv0 + kv) * DD + g];
#pragma unroll
      for (int jj = 0; jj < 8; ++jj) Vt[g + jj][kv] = vv[jj];
    }
    __syncthreads();

    // QK^T: s[g] is 16q x 16kv fragment (cols kv0+16g+l15, rows q0+16w+4*l4+r)
    floatx4 s[4];
#pragma unroll
    for (int g = 0; g < 4; ++g) {
      floatx4 a = (floatx4){0.f, 0.f, 0.f, 0.f};
      a = __builtin_amdgcn_mfma_f32_16x16x32_bf16(
          aq[0], *(const short8*)&Klds[g * 16 + l15][l4 * 8], a, 0, 0, 0);
      a = __builtin_amdgcn_mfma_f32_16x16x32_bf16(
          aq[1], *(const short8*)&Klds[g * 16 + l15][32 + l4 * 8], a, 0, 0, 0);
      s[g] = a;
    }

    // bias add + running max
    const size_t brow = ((size_t)b * SS + (q0 + wave * 16 + l4 * 4)) * SS + kv0 + l15;
    float tmax[4];
#pragma unroll
    for (int r = 0; r < 4; ++r) tmax[r] = -1e30f;
#pragma unroll
    for (int g = 0; g < 4; ++g)
#pragma unroll
      for (int r = 0; r < 4; ++r) {
        float val = s[g][r] + bf2f(biasb[brow + (size_t)r * SS + g * 16]);
        s[g][r] = val;
        tmax[r] = fmaxf(tmax[r], val);
      }
#pragma unroll
    for (int r = 0; r < 4; ++r)
      for (int m = 1; m < 16; m <<= 1) tmax[r] = fmaxf(tmax[r], __shfl_xor(tmax[r], m));

    float fac[4], rsum[4];
#pragma unroll
    for (int r = 0; r < 4; ++r) {
      float mnew = fmaxf(mrun[r], tmax[r]);
      fac[r] = __expf(mrun[r] - mnew);
      mrun[r] = mnew;
      rsum[r] = 0.f;
    }
#pragma unroll
    for (int g = 0; g < 4; ++g)
#pragma unroll
      for (int r = 0; r < 4; ++r) {
        float p = __expf(s[g][r] - mrun[r]);
        s[g][r] = p;
        rsum[r] += p;
      }
#pragma unroll
    for (int r = 0; r < 4; ++r) {
      for (int m = 1; m < 16; m <<= 1) rsum[r] += __shfl_xor(rsum[r], m);
      ssum[r] = ssum[r] * fac[r] + rsum[r];
    }
#pragma unroll
    for (int dg = 0; dg < 4; ++dg)
#pragma unroll
      for (int r = 0; r < 4; ++r) acc_o[dg][r] *= fac[r];

    // P -> LDS (bf16), then PV
#pragma unroll
    for (int g = 0; g < 4; ++g)
#pragma unroll
      for (int r = 0; r < 4; ++r)
        Plds[wave][l4 * 4 + r][g * 16 + l15] = f2bf(s[g][r]);
    __syncthreads();

#pragma unroll
    for (int kk = 0; kk < 2; ++kk) {
      short8 pf = *(const short8*)&Plds[wave][l15][kk * 32 + l4 * 8];
#pragma unroll
      for (int dg = 0; dg < 4; ++dg) {
        short8 vf = *(const short8*)&Vt[dg * 16 + l15][kk * 32 + l4 * 8];
        acc_o[dg] = __builtin_amdgcn_mfma_f32_16x16x32_bf16(pf, vf, acc_o[dg], 0, 0, 0);
      }
    }
  }

  short* Ob = O + (size_t)b * SS * DD + headoff;
#pragma unroll
  for (int r = 0; r < 4; ++r) {
    float inv = 1.0f / ssum[r];
    int orow = q0 + wave * 16 + l4 * 4 + r;
#pragma unroll
    for (int dg = 0; dg < 4; ++dg)
      Ob[(size_t)orow * DD + dg * 16 + l15] = f2bf(acc_o[dg][r] * inv);
  }
}

// ---------------- launch ----------------
extern "C" void kernel_launch(void* const* d_in, const int* in_sizes, int n_in,
                              void* d_out, int out_size, void* d_ws, size_t ws_size,
                              hipStream_t stream) {
  const float* qa   = (const float*)d_in[0];
  const float* ma   = (const float*)d_in[1];
  const float* bias = (const float*)d_in[2];
  const float* Wq   = (const float*)d_in[3];
  const float* Wk   = (const float*)d_in[4];
  const float* Wv   = (const float*)d_in[5];
  const float* Wo   = (const float*)d_in[6];
  float* out = (float*)d_out;

  char* ws = (char*)d_ws;
  size_t off = 0;
  auto alloc = [&](size_t bytes) {
    char* p = ws + off;
    off += (bytes + 255) & ~(size_t)255;
    return p;
  };
  const size_t nQKV = (size_t)BB * SS * DD;     // 8.4M elems
  short* qa_bf   = (short*)alloc(nQKV * 2);
  short* ma_bf   = (short*)alloc(nQKV * 2);
  short* bias_bf = (short*)alloc((size_t)BB * SS * SS * 2);
  short* Wqt = (short*)alloc((size_t)DD * DD * 2);
  short* Wkt = (short*)alloc((size_t)DD * DD * 2);
  short* Wvt = (short*)alloc((size_t)DD * DD * 2);
  short* Wot = (short*)alloc((size_t)DD * DD * 2);
  short* Qp  = (short*)alloc(nQKV * 2);
  short* Kp  = (short*)alloc(nQKV * 2);
  short* Vp  = (short*)alloc(nQKV * 2);
  short* AOp = (short*)alloc(nQKV * 2);

  int n4a = (int)(nQKV / 4);
  int n4b = BB * SS * SS / 4;
  cvt_kernel<<<(n4a + 255) / 256, 256, 0, stream>>>(qa, qa_bf, n4a);
  cvt_kernel<<<(n4a + 255) / 256, 256, 0, stream>>>(ma, ma_bf, n4a);
  cvt_kernel<<<(n4b + 255) / 256, 256, 0, stream>>>(bias, bias_bf, n4b);

  dim3 tg(64, 64);
  wtrans_kernel<<<tg, 256, 0, stream>>>(Wq, Wqt, 0.125f);  // fold DH^-0.5
  wtrans_kernel<<<tg, 256, 0, stream>>>(Wk, Wkt, 1.0f);
  wtrans_kernel<<<tg, 256, 0, stream>>>(Wv, Wvt, 1.0f);
  wtrans_kernel<<<tg, 256, 0, stream>>>(Wo, Wot, 1.0f);

  dim3 gg(BB * SS / 128, DD / 128);  // (64, 8)
  gemm_kernel<0><<<gg, 256, 0, stream>>>(qa_bf, Wqt, Qp, BB * SS, DD, DD);
  gemm_kernel<0><<<gg, 256, 0, stream>>>(ma_bf, Wkt, Kp, BB * SS, DD, DD);
  gemm_kernel<0><<<gg, 256, 0, stream>>>(ma_bf, Wvt, Vp, BB * SS, DD, DD);

  attn_kernel<<<dim3(BB * HH, SS / 64), 256, 0, stream>>>(Qp, Kp, Vp, bias_bf, AOp);

  gemm_kernel<1><<<gg, 256, 0, stream>>>(AOp, Wot, out, BB * SS, DD, DD);
}